// Round 2
// baseline (243.722 us; speedup 1.0000x reference)
//
#include <hip/hip_runtime.h>

#define RR 4
#define NS 17
#define BB 4
#define CC 128
#define HH 96
#define WW 160
#define HWSZ (HH * WW)

// Block: 32 (w) x 8 (h); each thread owns ONE pixel.
// Pixel tile: 8 rows x 32 cols. LDS tgt tile: 16 x 40 (halo R=4 each side),
// vectorized over 4 consecutive channels (float4 per element), double-buffered.
#define TW 32
#define HTILE 8
#define TROWS (HTILE + 2 * RR)   // 16
#define TCOLS (TW + 2 * RR)      // 40
#define TILE_E (TROWS * TCOLS)   // 640 float4 = 10240 B per buffer
#define CCHUNK 16                // channels per block (8 chunks, atomic-accumulated)
#define NCHUNK (CC / CCHUNK)     // 8
#define CG 4                     // channels per group (float4)
#define NG (CCHUNK / CG)         // 4 groups per block
#define NSPX (WW / TW)           // 5
#define NSPY (HH / HTILE)        // 12
#define NSP (NSPX * NSPY)        // 60 spatial tiles
#define NWG (NSP * BB * NCHUNK)  // 1920 workgroups
#define NXCD 8
#define WGPX (NWG / NXCD)        // 240 (exact)

#define FMA4(a, t) \
    (a) = fmaf(svx, (t).x, fmaf(svy, (t).y, fmaf(svz, (t).z, fmaf(svw, (t).w, (a)))))

__global__ __launch_bounds__(256, 6)
void cost_volume_kernel(const float* __restrict__ src,
                        const float* __restrict__ tgt,
                        float* __restrict__ out) {
    __shared__ float4 tile[2][TILE_E];    // 20480 B

    const int x   = threadIdx.x;          // 0..31
    const int hg  = threadIdx.y;          // 0..7
    const int tid = hg * TW + x;          // 0..255

    // XCD-aware bijective swizzle: each XCD gets a contiguous wg range.
    // Per XCD, 240 wgs = 4 z-slices (one (b, chunk) each, ~1 MB tgt) ->
    // halo re-reads stay in that XCD's L2.
    const int flat = blockIdx.x;                      // 0..1919
    const int wg   = (flat & (NXCD - 1)) * WGPX + (flat >> 3);
    const int sp   = wg % NSP;                        // spatial tile (x-fastest)
    const int z    = wg / NSP;                        // 0..31 = b*? + chunk
    const int wx   = sp % NSPX;
    const int wy   = sp / NSPX;

    const int w0 = wx * TW;
    const int h0 = wy * HTILE;
    const int b  = z & 3;
    const int c0 = (z >> 2) * CCHUNK;

    const int w = w0 + x;                 // always < WW
    const int h = h0 + hg;                // always < HH

    const float* tgt_b = tgt + (size_t)(b * CC + c0) * HWSZ;
    const float* src_p = src + (size_t)(b * CC + c0) * HWSZ + h * WW + w;

    // --- staging slots (invariant across channel groups) ---
    int  sOff[3];
    bool sVal[3];
#pragma unroll
    for (int k = 0; k < 3; ++k) {
        const int idx = tid + k * 256;
        const int r   = idx / TCOLS;
        const int col = idx - r * TCOLS;
        const int gr  = h0 - RR + r;
        const int gc  = w0 - RR + col;
        sVal[k] = (idx < TILE_E) && gr >= 0 && gr < HH && gc >= 0 && gc < WW;
        sOff[k] = gr * WW + gc;
    }

    float4 pre[3];                        // tgt tile prefetch (3 f4/thread)
    float  svc[4];                        // src: current group
    float  svn[4];                        // src: next group (prefetch)

    auto fetch = [&](int g, float sv[4]) {
        const float* t = tgt_b + (size_t)(g * CG) * HWSZ;
#pragma unroll
        for (int k = 0; k < 3; ++k) {
            float4 v = make_float4(0.f, 0.f, 0.f, 0.f);
            if (sVal[k]) {
                const float* p = t + sOff[k];
                v.x = p[0];
                v.y = p[HWSZ];
                v.z = p[2 * HWSZ];
                v.w = p[3 * HWSZ];
            }
            pre[k] = v;
        }
        const float* s = src_p + (size_t)(g * CG) * HWSZ;
#pragma unroll
        for (int k = 0; k < 4; ++k) sv[k] = s[k * HWSZ];
    };

    auto store_tile = [&](int buf) {
        tile[buf][tid]       = pre[0];
        tile[buf][tid + 256] = pre[1];
        if (tid + 512 < TILE_E) tile[buf][tid + 512] = pre[2];
    };

    float acc[NS];
#pragma unroll
    for (int s = 0; s < NS; ++s) acc[s] = 0.f;

    // prologue: stage group 0 into buffer 0
    fetch(0, svc);
    store_tile(0);
    __syncthreads();

    const int base = (RR + hg) * TCOLS + (RR + x);

#pragma unroll
    for (int g = 0; g < NG; ++g) {
        const int cur = g & 1;

        // issue next group's global loads early (latency hides under compute)
        if (g + 1 < NG) fetch(g + 1, svn);

        // compute: 17 ds_read_b128 + 68 FMAs (4 channels at once)
        {
            const float svx = svc[0], svy = svc[1], svz = svc[2], svw = svc[3];
            const float4* tb = tile[cur];
            float4 tc = tb[base];
            FMA4(acc[0], tc);
#pragma unroll
            for (int off = 1; off <= RR; ++off) {
                float4 tu = tb[base - off * TCOLS];
                float4 td = tb[base + off * TCOLS];
                float4 tl = tb[base - off];
                float4 tr = tb[base + off];
                FMA4(acc[4 * off - 3], tu);
                FMA4(acc[4 * off - 2], td);
                FMA4(acc[4 * off - 1], tl);
                FMA4(acc[4 * off    ], tr);
            }
        }

        // write-late: stage next group into the other buffer, then ONE barrier
        if (g + 1 < NG) {
            store_tile(cur ^ 1);
#pragma unroll
            for (int k = 0; k < 4; ++k) svc[k] = svn[k];
            __syncthreads();
        }
    }

    // epilogue: atomic accumulate (8 channel-chunks race per output)
    float* op = out + (((size_t)b * NS) * HH + h) * WW + w;
#pragma unroll
    for (int s = 0; s < NS; ++s) {
        atomicAdd(op + (size_t)s * HWSZ, acc[s]);
    }
}

extern "C" void kernel_launch(void* const* d_in, const int* in_sizes, int n_in,
                              void* d_out, int out_size, void* d_ws, size_t ws_size,
                              hipStream_t stream) {
    const float* src = (const float*)d_in[0];
    const float* tgt = (const float*)d_in[1];
    float* out = (float*)d_out;

    // d_out is poisoned before every launch; we accumulate atomically -> zero it
    hipMemsetAsync(out, 0, (size_t)out_size * sizeof(float), stream);

    dim3 block(TW, 8, 1);      // 256 threads
    dim3 grid(NWG, 1, 1);      // 1920 blocks
    cost_volume_kernel<<<grid, block, 0, stream>>>(src, tgt, out);
}